// Round 1
// baseline (78.481 us; speedup 1.0000x reference)
//
#include <hip/hip_runtime.h>

// Problem constants (from reference):
//   x  : (1, 24, 56, 56) f32
//   w0 : (96, 9, 14)     f32
//   w1 : (24, 2, 14)     f32
//   out: (1, 96, 56, 56) f32
//
// Index algebra (derived from einsum/pad/unfold/roll/sum chain):
//   B[k][h][j] = sum_c x[c,m,h] * w1[c,k,j]          (h in [0,56), zero outside)
//   S[kh,n,j]  = B[1][(n+55)%56 + kh - 4][j] + B[0][n + kh - 4][j]
//   out[i,m,n] = sum_{kh<9,j<14} w0[i,kh,j] * S[kh,n,j]

#define MDIM 56
#define NDIM 56
#define CIN  24
#define JD   14
#define KHD  9
#define IOUT 96
#define ITILE 24          // i's per block (96 / gridDim.y)
#define BP   15           // padded row stride for sB (kills n vs n+16 bank conflict)

__global__ __launch_bounds__(256) void fused_shift_conv(
    const float* __restrict__ x,    // [24][56][56]
    const float* __restrict__ w0,   // [96][9][14]
    const float* __restrict__ w1,   // [24][2][14]
    float* __restrict__ out)        // [96][56][56]
{
    const int m     = blockIdx.x;   // 0..55
    const int itile = blockIdx.y;   // 0..3
    const int tid   = threadIdx.x;

    __shared__ float sx[CIN * MDIM];            // 1344 : x[c][m][h] -> [c][h]
    __shared__ float sw1[CIN * 2 * JD];         // 672
    __shared__ float sw0[ITILE * KHD * JD];     // 3024 : this block's 24 w0 rows
    __shared__ float sB[2 * 64 * BP];           // 1920 : B padded to hp in [0,64)

    // ---- stage inputs into LDS --------------------------------------------
    for (int e = tid; e < CIN * MDIM; e += 256) {
        int c = e / MDIM, h = e % MDIM;
        sx[e] = x[(c * MDIM + m) * NDIM + h];   // x[c*3136 + m*56 + h]
    }
    for (int e = tid; e < CIN * 2 * JD; e += 256)
        sw1[e] = w1[e];
    for (int e = tid; e < ITILE * KHD * JD; e += 256)
        sw0[e] = w0[itile * ITILE * KHD * JD + e];
    for (int e = tid; e < 2 * 64 * BP; e += 256)
        sB[e] = 0.0f;                           // zero incl. the +/-4 halo pads
    __syncthreads();

    // ---- phase 1: B[k][h][j] = sum_c sx[c][h] * sw1[c][k][j] ---------------
    for (int e = tid; e < 2 * MDIM * JD; e += 256) {
        int k = e / (MDIM * JD);
        int r = e % (MDIM * JD);
        int h = r / JD;
        int j = r % JD;
        float acc = 0.0f;
        #pragma unroll
        for (int c = 0; c < CIN; ++c)
            acc += sx[c * MDIM + h] * sw1[(c * 2 + k) * JD + j];
        sB[(k * 64 + (h + 4)) * BP + j] = acc;  // hp = h + 4
    }
    __syncthreads();

    // ---- phase 2: out[i,m,n] -----------------------------------------------
    for (int e = tid; e < ITILE * NDIM; e += 256) {
        int il = e / NDIM;            // local i
        int n  = e % NDIM;
        int h1 = (n + 55) % 56;       // roll-by-1: previous h (wraps)
        // hp index for B0 is n + kh (== (n+kh-4) + 4), for B1 it's h1 + kh
        const float* b0  = &sB[(0 * 64 + n ) * BP];
        const float* b1  = &sB[(1 * 64 + h1) * BP];
        const float* w0r = &sw0[il * KHD * JD];
        float acc = 0.0f;
        #pragma unroll
        for (int kh = 0; kh < KHD; ++kh) {
            #pragma unroll
            for (int j = 0; j < JD; ++j) {
                acc += w0r[kh * JD + j] * (b1[kh * BP + j] + b0[kh * BP + j]);
            }
        }
        int i = itile * ITILE + il;
        out[(i * MDIM + m) * NDIM + n] = acc;   // coalesced in n
    }
}

extern "C" void kernel_launch(void* const* d_in, const int* in_sizes, int n_in,
                              void* d_out, int out_size, void* d_ws, size_t ws_size,
                              hipStream_t stream) {
    const float* x  = (const float*)d_in[0];
    const float* w0 = (const float*)d_in[1];
    const float* w1 = (const float*)d_in[2];
    float* out = (float*)d_out;

    dim3 grid(MDIM, IOUT / ITILE);  // (56, 4)
    dim3 block(256);
    fused_shift_conv<<<grid, block, 0, stream>>>(x, w0, w1, out);
}

// Round 2
// 72.135 us; speedup vs baseline: 1.0880x; 1.0880x over previous
//
#include <hip/hip_runtime.h>

// Problem constants (from reference):
//   x  : (1, 24, 56, 56) f32
//   w0 : (96, 9, 14)     f32
//   w1 : (24, 2, 14)     f32
//   out: (1, 96, 56, 56) f32
//
// Index algebra (derived from einsum/pad/unfold/roll/sum chain):
//   B[k][h][j] = sum_c x[c,m,h] * w1[c,k,j]          (h in [0,56), zero outside)
//   S[kh,n,j]  = B[1][(n+55)%56 + kh - 4][j] + B[0][n + kh - 4][j]
//   out[i,m,n] = sum_{kh<9,j<14} w0[i,kh,j] * S[kh,n,j]

#define MDIM 56
#define NDIM 56
#define CIN  24
#define JD   14
#define KHD  9
#define IOUT 96
#define ITILE 24          // i's per block (96 / gridDim.y)
#define BP   15           // padded row stride (conflict-free for stride-1 row access)

// Phase-2b register tiling: each thread owns 3 il's x 2 n's.
#define TIL 3             // il per thread
#define TNN 2             // n per thread
#define NGRP (ITILE / TIL)          // 8 il-groups
#define NBLK (NDIM / TNN)           // 28 n-groups -> 224 active threads

__global__ __launch_bounds__(256) void fused_shift_conv(
    const float* __restrict__ x,    // [24][56][56]
    const float* __restrict__ w0,   // [96][9][14]
    const float* __restrict__ w1,   // [24][2][14]
    float* __restrict__ out)        // [96][56][56]
{
    const int m     = blockIdx.x;   // 0..55
    const int itile = blockIdx.y;   // 0..3
    const int tid   = threadIdx.x;

    __shared__ float sx[CIN * MDIM];            // 1344 : x[c][m][h] -> [c][h]
    __shared__ float sw1[CIN * 2 * JD];         // 672
    __shared__ float sw0[ITILE * KHD * JD];     // 3024 : this block's 24 w0 rows
    __shared__ float sB[2 * 64 * BP];           // 1920 : B padded, hp = h+4 in [0,64)
    __shared__ float sS[KHD * NDIM * BP];       // 7560 : S[kh][n][j]

    // ---- stage inputs into LDS --------------------------------------------
    for (int e = tid; e < CIN * MDIM; e += 256) {
        int c = e / MDIM, h = e % MDIM;
        sx[e] = x[(c * MDIM + m) * NDIM + h];
    }
    for (int e = tid; e < CIN * 2 * JD; e += 256)
        sw1[e] = w1[e];
    for (int e = tid; e < ITILE * KHD * JD; e += 256)
        sw0[e] = w0[itile * ITILE * KHD * JD + e];
    for (int e = tid; e < 2 * 64 * BP; e += 256)
        sB[e] = 0.0f;                           // zero incl. the +/-4 halo pads
    __syncthreads();

    // ---- phase 1: B[k][h][j] = sum_c sx[c][h] * sw1[c][k][j] ---------------
    for (int e = tid; e < 2 * MDIM * JD; e += 256) {
        int k = e / (MDIM * JD);
        int r = e % (MDIM * JD);
        int h = r / JD;
        int j = r % JD;
        float acc = 0.0f;
        #pragma unroll
        for (int c = 0; c < CIN; ++c)
            acc += sx[c * MDIM + h] * sw1[(c * 2 + k) * JD + j];
        sB[(k * 64 + (h + 4)) * BP + j] = acc;  // hp = h + 4
    }
    __syncthreads();

    // ---- phase 2a: S[kh][n][j] = B0[n+kh] + B1[h1+kh]  (padded indices) ----
    for (int e = tid; e < KHD * NDIM * JD; e += 256) {
        int kh = e / (NDIM * JD);
        int r  = e % (NDIM * JD);
        int n  = r / JD;
        int j  = r % JD;
        int h1 = (n + 55) % 56;
        sS[(kh * NDIM + n) * BP + j] =
            sB[(0 * 64 + (n  + kh)) * BP + j] +
            sB[(1 * 64 + (h1 + kh)) * BP + j];
    }
    __syncthreads();

    // ---- phase 2b: out[i,m,n] = sum_{kh,j} w0[i,kh,j] * S[kh,n,j] ----------
    // thread t (< 224): il0 = 3*(t%8), n0 = 2*(t/8)
    if (tid < NGRP * NBLK) {
        const int il0 = TIL * (tid % NGRP);
        const int n0  = TNN * (tid / NGRP);

        float acc[TIL][TNN];
        #pragma unroll
        for (int a = 0; a < TIL; ++a)
            #pragma unroll
            for (int b = 0; b < TNN; ++b)
                acc[a][b] = 0.0f;

        const float* w0a = &sw0[(il0 + 0) * KHD * JD];
        const float* w0b = &sw0[(il0 + 1) * KHD * JD];
        const float* w0c = &sw0[(il0 + 2) * KHD * JD];

        #pragma unroll
        for (int kh = 0; kh < KHD; ++kh) {
            const float* s0 = &sS[(kh * NDIM + n0) * BP];
            const float* s1 = s0 + BP;
            const float* wa = w0a + kh * JD;
            const float* wb = w0b + kh * JD;
            const float* wc = w0c + kh * JD;
            #pragma unroll
            for (int j = 0; j < JD; ++j) {
                float v0 = s0[j], v1 = s1[j];
                float a0 = wa[j], a1 = wb[j], a2 = wc[j];
                acc[0][0] += a0 * v0;  acc[0][1] += a0 * v1;
                acc[1][0] += a1 * v0;  acc[1][1] += a1 * v1;
                acc[2][0] += a2 * v0;  acc[2][1] += a2 * v1;
            }
        }

        #pragma unroll
        for (int a = 0; a < TIL; ++a) {
            int i = itile * ITILE + il0 + a;
            float* o = &out[(i * MDIM + m) * NDIM + n0];
            o[0] = acc[a][0];
            o[1] = acc[a][1];
        }
    }
}

extern "C" void kernel_launch(void* const* d_in, const int* in_sizes, int n_in,
                              void* d_out, int out_size, void* d_ws, size_t ws_size,
                              hipStream_t stream) {
    const float* x  = (const float*)d_in[0];
    const float* w0 = (const float*)d_in[1];
    const float* w1 = (const float*)d_in[2];
    float* out = (float*)d_out;

    dim3 grid(MDIM, IOUT / ITILE);  // (56, 4)
    dim3 block(256);
    fused_shift_conv<<<grid, block, 0, stream>>>(x, w0, w1, out);
}

// Round 3
// 65.459 us; speedup vs baseline: 1.1989x; 1.1020x over previous
//
#include <hip/hip_runtime.h>

// Problem constants (from reference):
//   x  : (1, 24, 56, 56) f32
//   w0 : (96, 9, 14)     f32
//   w1 : (24, 2, 14)     f32   (flat [c][kj], kj = k*14+j, 28 wide)
//   out: (1, 96, 56, 56) f32
//
// Index algebra (derived from einsum/pad/unfold/roll/sum chain):
//   B[h][kj]   = sum_c x[c,m,h] * w1[c,kj]           (h in [0,56), zero outside)
//   S[kh,n,j]  = B[(n+kh-4)][j] + B[((n+55)%56 + kh - 4)][14+j]
//   out[i,m,n] = sum_{kh<9,j<14} w0[i,kh,j] * S[kh,n,j]
// B stored padded: hp = h+4 in [0,64), halo rows zeroed.

#define MDIM 56
#define NDIM 56
#define CIN  24
#define JD   14
#define KJD  28
#define KHD  9
#define IOUT 96
#define ITILE 24
#define TIL 3
#define TNN 2

__global__ __launch_bounds__(256) void fused_shift_conv(
    const float* __restrict__ x,    // [24][56][56]
    const float* __restrict__ w0,   // [96][9][14]
    const float* __restrict__ w1,   // [24][28]
    float* __restrict__ out)        // [96][56][56]
{
    const int m     = blockIdx.x;   // 0..55
    const int itile = blockIdx.y;   // 0..3
    const int tid   = threadIdx.x;

    // All row strides are multiples of 14 floats = 56 B -> every row 8B-aligned.
    __shared__ __align__(16) float sx [CIN * MDIM];         // [c][h]      1344
    __shared__ __align__(16) float sw1[CIN * KJD];          // [c][kj]      672
    __shared__ __align__(16) float sw0[ITILE * KHD * JD];   // [il][kh][j] 3024
    __shared__ __align__(16) float sB [64 * KJD];           // [hp][kj]    1792
    __shared__ __align__(16) float sS [KHD * NDIM * JD];    // [kh][n][j]  7056

    // ---- stage inputs into LDS (float4) ------------------------------------
    {
        float4*       sx4  = (float4*)sx;
        float4*       sw14 = (float4*)sw1;
        float4*       sw04 = (float4*)sw0;
        float4*       sB4  = (float4*)sB;
        const float4* x4   = (const float4*)x;
        const float4* w14  = (const float4*)w1;
        const float4* w04  = (const float4*)w0;

        for (int e = tid; e < CIN * JD; e += 256) {          // 336 float4 of x
            int c = e / JD, t = e % JD;
            sx4[e] = x4[c * 784 + m * JD + t];               // x[c][m][4t..]
        }
        for (int e = tid; e < (CIN * KJD) / 4; e += 256)     // 168 float4
            sw14[e] = w14[e];
        for (int e = tid; e < (ITILE * KHD * JD) / 4; e += 256) // 756 float4
            sw04[e] = w04[itile * (ITILE * KHD * JD / 4) + e];
        // zero only sB halo rows hp in {0..3, 60..63}: 8 rows x 28 = 56 float4
        for (int e = tid; e < 56; e += 256) {
            int r = e / 7;
            int hp = r + (r >= 4 ? 56 : 0);
            sB4[hp * 7 + (e % 7)] = make_float4(0.f, 0.f, 0.f, 0.f);
        }
    }
    __syncthreads();

    // ---- phase 1: B[h][kj] = sum_c x[c,h] * w1[c,kj], tiled 2h x 4kj -------
    if (tid < 196) {                      // 28 h-groups x 7 kj-groups
        const int g   = tid / 7;          // h-group
        const int q   = tid % 7;          // kj-group
        const int h0  = 2 * g;
        const int kj0 = 4 * q;

        float4 acc0 = make_float4(0.f, 0.f, 0.f, 0.f);
        float4 acc1 = make_float4(0.f, 0.f, 0.f, 0.f);
        #pragma unroll
        for (int c = 0; c < CIN; ++c) {
            float2 xv = *(const float2*)&sx[c * MDIM + h0];
            float4 wv = *(const float4*)&sw1[c * KJD + kj0];
            acc0.x += xv.x * wv.x;  acc0.y += xv.x * wv.y;
            acc0.z += xv.x * wv.z;  acc0.w += xv.x * wv.w;
            acc1.x += xv.y * wv.x;  acc1.y += xv.y * wv.y;
            acc1.z += xv.y * wv.z;  acc1.w += xv.y * wv.w;
        }
        *(float4*)&sB[(h0 + 4) * KJD + kj0] = acc0;   // hp = h+4
        *(float4*)&sB[(h0 + 5) * KJD + kj0] = acc1;
    }
    __syncthreads();

    // ---- phase 2a: S[kh][n][j] = B[n+kh][j] + B[h1+kh][14+j]  (float2) -----
    for (int e = tid; e < KHD * NDIM * 7; e += 256) {
        int kh = e / (NDIM * 7);
        int r  = e % (NDIM * 7);
        int n  = r / 7;
        int j2 = 2 * (r % 7);
        int h1 = (n + 55) % 56;
        float2 a = *(const float2*)&sB[(n  + kh) * KJD + j2];
        float2 b = *(const float2*)&sB[(h1 + kh) * KJD + JD + j2];
        *(float2*)&sS[(kh * NDIM + n) * JD + j2] = make_float2(a.x + b.x, a.y + b.y);
    }
    __syncthreads();

    // ---- phase 2b: out[i,m,n] = sum_{kh,j} w0[i,kh,j] * S[kh,n,j] ----------
    // thread t (< 224): il0 = 3*(t%8), n0 = 2*(t/8). All float2 reads;
    // row strides 14 -> lane-group rows map to distinct banks (conflict-free).
    if (tid < (ITILE / TIL) * (NDIM / TNN)) {
        const int il0 = TIL * (tid % (ITILE / TIL));
        const int n0  = TNN * (tid / (ITILE / TIL));

        float acc[TIL][TNN] = {};

        #pragma unroll
        for (int kh = 0; kh < KHD; ++kh) {
            const float2* s0 = (const float2*)&sS[(kh * NDIM + n0    ) * JD];
            const float2* s1 = (const float2*)&sS[(kh * NDIM + n0 + 1) * JD];
            const float2* wa = (const float2*)&sw0[((il0 + 0) * KHD + kh) * JD];
            const float2* wb = (const float2*)&sw0[((il0 + 1) * KHD + kh) * JD];
            const float2* wc = (const float2*)&sw0[((il0 + 2) * KHD + kh) * JD];
            #pragma unroll
            for (int j2 = 0; j2 < 7; ++j2) {
                float2 v0 = s0[j2], v1 = s1[j2];
                float2 A = wa[j2], B = wb[j2], C = wc[j2];
                acc[0][0] += A.x * v0.x + A.y * v0.y;
                acc[0][1] += A.x * v1.x + A.y * v1.y;
                acc[1][0] += B.x * v0.x + B.y * v0.y;
                acc[1][1] += B.x * v1.x + B.y * v1.y;
                acc[2][0] += C.x * v0.x + C.y * v0.y;
                acc[2][1] += C.x * v1.x + C.y * v1.y;
            }
        }

        #pragma unroll
        for (int a = 0; a < TIL; ++a) {
            int i = itile * ITILE + il0 + a;
            *(float2*)&out[(i * MDIM + m) * NDIM + n0] =
                make_float2(acc[a][0], acc[a][1]);
        }
    }
}

extern "C" void kernel_launch(void* const* d_in, const int* in_sizes, int n_in,
                              void* d_out, int out_size, void* d_ws, size_t ws_size,
                              hipStream_t stream) {
    const float* x  = (const float*)d_in[0];
    const float* w0 = (const float*)d_in[1];
    const float* w1 = (const float*)d_in[2];
    float* out = (float*)d_out;

    dim3 grid(MDIM, IOUT / ITILE);  // (56, 4)
    dim3 block(256);
    fused_shift_conv<<<grid, block, 0, stream>>>(x, w0, w1, out);
}